// Round 3
// baseline (2741.852 us; speedup 1.0000x reference)
//
#include <hip/hip_runtime.h>
#include <cmath>

#define NB   16
#define LL   1024
#define DD   512
#define NCLS 64

// ---------------------------------------------------------------- scan helpers
// 8-lane-group sum via DPP (VALU cross-lane) instead of ds_swizzle (LDS pipe).
template<int CTRL>
__device__ __forceinline__ float dpp_add(float x) {
  int s = __builtin_amdgcn_update_dpp(0, __float_as_int(x), CTRL, 0xF, 0xF, true);
  return x + __int_as_float(s);
}
__device__ __forceinline__ float wave_red8(float y) {
  y = dpp_add<0xB1>(y);    // quad_perm xor1
  y = dpp_add<0x4E>(y);    // quad_perm xor2
  y = dpp_add<0x141>(y);   // row_half_mirror (other quad of the 8-group)
  return y;
}

// fast tanh via v_exp_f32 + v_rcp_f32; |err|~1e-7, recurrence contractive.
__device__ __forceinline__ float fast_tanh(float x) {
  float e = __expf(2.0f * x);
  return 1.0f - __fdividef(2.0f, 1.0f + e);
}

__device__ __forceinline__ float poll_ld(const float* p) {
  return __hip_atomic_load(p, __ATOMIC_RELAXED, __HIP_MEMORY_SCOPE_AGENT);
}
__device__ __forceinline__ void enc_st(float* p, float v) {
  __hip_atomic_store(p, v + 2.0f, __ATOMIC_RELAXED, __HIP_MEMORY_SCOPE_AGENT);
}
__device__ __forceinline__ float min8(const float* h) {
  return fminf(fminf(fminf(h[0],h[1]),fminf(h[2],h[3])),
               fminf(fminf(h[4],h[5]),fminf(h[6],h[7])));
}
// 64-MAC dot with 4 independent accumulation chains (float4 components).
__device__ __forceinline__ void dot64(const float* w, const float4* h4, float4& a) {
  #pragma unroll
  for (int q = 0; q < 16; ++q) {
    float4 h = h4[q];
    a.x += w[4*q+0]*h.x; a.y += w[4*q+1]*h.y;
    a.z += w[4*q+2]*h.z; a.w += w[4*q+3]*h.w;
  }
}
__device__ __forceinline__ float hsum4(const float4& a) { return (a.x+a.y)+(a.z+a.w); }

// ------------------------------------------------- persistent 2-layer RNN scan
// 512 WGs = 2 layers x 16 batches x 16 WGs (2 WGs/CU, all co-resident).
// XCD locality: g%8 == b%8 for both halves.
//  * No k_gemm_embed: layer-1 WGs pin Wih1 too (+64 w/thread), gather
//    emb[x[b,t]] per step (prefetched 1 step ahead; loads issued post-discovery
//    so their vmcnt wait merges into the next poll spin), and compute the
//    x-projection themselves. The e-dot runs BEFORE the h-poll (off-chain).
//  * Zero barriers in the loop: each WAVE polls all 512 h values itself
//    (8 coalesced polls/thread, stride 64) and stages into wave-private LDS
//    (68-stride => conflict-free float4 reads). No cross-wave jitter max.
//  * All dots use 4 accumulator chains (dep chain 256cy -> ~70cy).
__global__ __launch_bounds__(256, 2) void k_scan(
    const int* __restrict__ x, const float* __restrict__ emb,
    const float* __restrict__ W_ih, const float* __restrict__ W_hh,
    const float* __restrict__ b_ih, const float* __restrict__ b_hh,
    float* __restrict__ Bbuf,   // h1+2 (encoded); starts harness-poisoned
    float* __restrict__ Abuf)   // h2+2 (O2, encoded); starts harness-poisoned
{
  const int g = blockIdx.x;
  const int lay = g >> 8;          // 0: h1 chain, 1: h2 chain
  const int b = g & 15;            // batch
  const int j = (g & 255) >> 4;    // WG index within (layer,batch) [0,16)
  const int tid = threadIdx.x;
  const int wv   = tid >> 6;       // wave [0,4)
  const int lane = tid & 63;
  const int part = tid & 7;        // k-part [0,8), 64 elems each
  const int rl   = tid >> 3;       // row_local [0,32)
  const int row  = j * 32 + rl;    // global hidden row
  const bool leader = (part == 0);

  // wave-private staging: value k lives at (k>>6)*68 + (k&63); thread polls
  // k = lane + 64c (coalesced 256B per instruction), writes word c*68+lane
  // (2-way bank alias = free); dot reads float4 at part*68+4q (conflict-free).
  __shared__ __align__(16) float lds[4 * 2 * 544];
  float* buf0 = lds + wv * 2 * 544;   // lay0: e stage ; lay1: h2 stage
  float* buf1 = buf0 + 544;           // lay0: h1 stage; lay1: h1 stage

  float* Bb = Bbuf + (long)b * LL * DD;
  float* Ab = Abuf + (long)b * LL * DD;

  if (lay == 0) {
    // -------- layer 1: h1(t) = tanh(Wih1.e(t) + bias1 + Whh1.h1(t-1)) -------
    float w0[64], w1[64];
    {
      const float* p0 = W_ih + (long)row * DD + part * 64;   // Wih layer0
      const float* p1 = W_hh + (long)row * DD + part * 64;   // Whh layer0
      #pragma unroll
      for (int q = 0; q < 64; ++q) { w0[q] = p0[q]; w1[q] = p1[q]; }
    }
    #pragma unroll
    for (int q = 0; q < 64; ++q) {
      asm volatile("" : "+v"(w0[q]));
      asm volatile("" : "+v"(w1[q]));
    }
    const float bias1 = b_ih[row] + b_hh[row];
    const int* xb = x + b * LL;

    float rE[8];
    // ---- t = 0: h1(0) = tanh(Wih1.e(0) + bias1) ----
    {
      const long tok0 = xb[0];
      const float* er = emb + tok0 * DD + lane;
      #pragma unroll
      for (int c = 0; c < 8; ++c) rE[c] = er[c * 64];
      #pragma unroll
      for (int c = 0; c < 8; ++c) buf0[c * 68 + lane] = rE[c];
      float4 aE = {0.f, 0.f, 0.f, 0.f};
      dot64(w0, (const float4*)(buf0 + part * 68), aE);
      float y = wave_red8(hsum4(aE));
      if (leader) enc_st(Bb + row, fast_tanh(y + bias1));
    }
    // prefetch e(1) into regs, x(2) into rTok
    int rTok;
    {
      const long tok1 = xb[1];
      const float* er = emb + tok1 * DD + lane;
      #pragma unroll
      for (int c = 0; c < 8; ++c) rE[c] = er[c * 64];
      rTok = xb[2];
    }
    for (int t = 1; t < LL; ++t) {
      // [A] commit e(t) regs->LDS (vmcnt for these loads aged ~1 full step)
      #pragma unroll
      for (int c = 0; c < 8; ++c) buf0[c * 68 + lane] = rE[c];
      // [C] e-dot (off the recurrence chain)
      float4 aE = {0.f, 0.f, 0.f, 0.f};
      dot64(w0, (const float4*)(buf0 + part * 68), aE);
      // [B] issue e(t+1) loads NOW: their vmcnt wait merges into the poll spin
      if (t + 1 < LL) {
        const float* er = emb + (long)rTok * DD + lane;
        #pragma unroll
        for (int c = 0; c < 8; ++c) rE[c] = er[c * 64];
        rTok = xb[(t + 2 < LL) ? (t + 2) : (LL - 1)];
      }
      // [D] per-wave poll of h1(t-1) — no barrier
      const float* s1 = Bb + (long)(t - 1) * DD + lane;
      float hv[8];
      #pragma unroll
      for (int c = 0; c < 8; ++c) hv[c] = poll_ld(s1 + 64 * c);
      float mn = min8(hv);
      while (mn <= 1.0f) {
        #pragma unroll
        for (int c = 0; c < 8; ++c) hv[c] = poll_ld(s1 + 64 * c);
        mn = min8(hv);
      }
      #pragma unroll
      for (int c = 0; c < 8; ++c) buf1[c * 68 + lane] = hv[c] - 2.0f;
      // [E] h-dot + finish
      float4 aH = {0.f, 0.f, 0.f, 0.f};
      dot64(w1, (const float4*)(buf1 + part * 68), aH);
      float y = wave_red8(hsum4(aE) + hsum4(aH));
      if (leader) enc_st(Bb + (long)t * DD + row, fast_tanh(y + bias1));
    }
  } else {
    // ------ layer 2: h2(t) = tanh(Wih2.h1(t) + bias2 + Whh2.h2(t-1)) --------
    float w2[64], w3[64];
    {
      const float* p2 = W_ih + (long)DD * DD + (long)row * DD + part * 64;
      const float* p3 = W_hh + (long)DD * DD + (long)row * DD + part * 64;
      #pragma unroll
      for (int q = 0; q < 64; ++q) { w2[q] = p2[q]; w3[q] = p3[q]; }
    }
    #pragma unroll
    for (int q = 0; q < 64; ++q) {
      asm volatile("" : "+v"(w2[q]));
      asm volatile("" : "+v"(w3[q]));
    }
    const float bias2 = b_ih[DD + row] + b_hh[DD + row];

    // prologue: xin2(0) = Wih2 . h1(0) + bias2
    float xin2;
    {
      const float* s1 = Bb + lane;
      float hv[8];
      #pragma unroll
      for (int c = 0; c < 8; ++c) hv[c] = poll_ld(s1 + 64 * c);
      float mn = min8(hv);
      while (mn <= 1.0f) {
        #pragma unroll
        for (int c = 0; c < 8; ++c) hv[c] = poll_ld(s1 + 64 * c);
        mn = min8(hv);
      }
      #pragma unroll
      for (int c = 0; c < 8; ++c) buf1[c * 68 + lane] = hv[c] - 2.0f;
      float4 a = {0.f, 0.f, 0.f, 0.f};
      dot64(w2, (const float4*)(buf1 + part * 68), a);
      xin2 = wave_red8(hsum4(a)) + bias2;
    }
    // iter t: store h2(t) (using xin2(t)), then compute xin2(t+1) from h1(t+1)
    // — M2 sits between the h2 store and the next poll, hiding store->poll.
    for (int t = 0; t < LL; ++t) {
      const bool st2 = (t >= 1);        // h2(t-1) exists
      const bool st1 = (t + 1 < LL);    // need h1(t+1)
      float uv[8], vv[8];
      const float* s2 = Ab + (long)(t - 1) * DD + lane;
      const float* s1 = Bb + (long)(t + 1) * DD + lane;
      #pragma unroll
      for (int c = 0; c < 8; ++c) { uv[c] = 3.f; vv[c] = 3.f; }
      if (st2) {
        #pragma unroll
        for (int c = 0; c < 8; ++c) uv[c] = poll_ld(s2 + 64 * c);
      }
      if (st1) {
        #pragma unroll
        for (int c = 0; c < 8; ++c) vv[c] = poll_ld(s1 + 64 * c);
      }
      float mn = fminf(min8(uv), min8(vv));
      while (mn <= 1.0f) {
        if (st2) {
          #pragma unroll
          for (int c = 0; c < 8; ++c) uv[c] = poll_ld(s2 + 64 * c);
        }
        if (st1) {
          #pragma unroll
          for (int c = 0; c < 8; ++c) vv[c] = poll_ld(s1 + 64 * c);
        }
        mn = fminf(min8(uv), min8(vv));
      }
      if (st2) {
        #pragma unroll
        for (int c = 0; c < 8; ++c) buf0[c * 68 + lane] = uv[c] - 2.0f;
      }
      if (st1) {
        #pragma unroll
        for (int c = 0; c < 8; ++c) buf1[c * 68 + lane] = vv[c] - 2.0f;
      }
      // M3: h2(t) = tanh(xin2(t) + Whh2 . h2(t-1))
      float y3 = 0.f;
      if (st2) {
        float4 a = {0.f, 0.f, 0.f, 0.f};
        dot64(w3, (const float4*)(buf0 + part * 68), a);
        y3 = hsum4(a);
      }
      y3 = wave_red8(y3);
      if (leader) enc_st(Ab + (long)t * DD + row, fast_tanh(xin2 + y3));
      // M2: xin2(t+1) = Wih2 . h1(t+1) + bias2 (off the h2 critical hop)
      if (st1) {
        float4 a = {0.f, 0.f, 0.f, 0.f};
        dot64(w2, (const float4*)(buf1 + part * 68), a);
        xin2 = wave_red8(hsum4(a)) + bias2;
      }
    }
  }
}

// ------------------------------------------- attention row @ eos + decode head
// O2 is stored ENCODED (h+2). Decode: q explicitly; scores via qsum trick;
// att_z via sum(p)=1 -> subtract 2 at the end.
__global__ __launch_bounds__(256) void k_attn(
    const float* __restrict__ O2, const int* __restrict__ eos,
    const float* __restrict__ Wc, const float* __restrict__ bc,
    const float* __restrict__ Wd, const float* __restrict__ bd,
    float* __restrict__ out)
{
  const int b = blockIdx.x;
  const int tid = threadIdx.x;
  const int te = eos[b];
  __shared__ __align__(16) float q[DD];
  __shared__ float ps[LL];
  __shared__ float red[256];
  __shared__ __align__(16) float din[2 * DD];
  __shared__ __align__(16) float dvec[DD];
  const float* Ob = O2 + (long)b * LL * DD;
  const float4* Ob4 = (const float4*)Ob;

  float qpart = 0.f;
  for (int i = tid; i < DD; i += 256) {
    float v = Ob[(long)te * DD + i] - 2.0f;   // decode
    q[i] = v; qpart += v;
  }
  red[tid] = qpart; __syncthreads();
  for (int off = 128; off > 0; off >>= 1) {
    if (tid < off) red[tid] += red[tid + off];
    __syncthreads();
  }
  const float qsum = red[0];
  __syncthreads();
  const float4* q4 = (const float4*)q;

  // masked scores: raw dot(o_enc, q) - 2*qsum == dot(o, q)
  for (int ss = tid; ss < LL; ss += 256) {
    float sc = -1.0e9f;
    if (ss < te) {
      float4 acc = {0.f, 0.f, 0.f, 0.f};
      for (int kq = 0; kq < 128; ++kq) {
        float4 o = Ob4[ss * 128 + kq];
        float4 qq = q4[kq];
        acc.x += o.x*qq.x; acc.y += o.y*qq.y; acc.z += o.z*qq.z; acc.w += o.w*qq.w;
      }
      sc = acc.x + acc.y + acc.z + acc.w - 2.0f * qsum;
    }
    ps[ss] = sc;
  }
  __syncthreads();
  float m = -3.0e38f;
  for (int ss = tid; ss < LL; ss += 256) m = fmaxf(m, ps[ss]);
  red[tid] = m; __syncthreads();
  for (int off = 128; off > 0; off >>= 1) {
    if (tid < off) red[tid] = fmaxf(red[tid], red[tid + off]);
    __syncthreads();
  }
  m = red[0]; __syncthreads();
  float lsum = 0.f;
  for (int ss = tid; ss < LL; ss += 256) {
    float e = expf(ps[ss] - m);
    ps[ss] = e; lsum += e;
  }
  __syncthreads();
  red[tid] = lsum; __syncthreads();
  for (int off = 128; off > 0; off >>= 1) {
    if (tid < off) red[tid] += red[tid + off];
    __syncthreads();
  }
  const float inv = 1.0f / red[0];
  __syncthreads();
  for (int ss = tid; ss < LL; ss += 256) ps[ss] *= inv;
  __syncthreads();

  // att_z (encoded: sum p*o_enc - 2 since sum p = 1), z-copy (already decoded)
  if (tid < 128) {
    float4 acc = {0.f, 0.f, 0.f, 0.f};
    for (int ss = 0; ss < LL; ++ss) {
      float p = ps[ss];
      if (p != 0.0f) {
        float4 o = Ob4[ss * 128 + tid];
        acc.x += p*o.x; acc.y += p*o.y; acc.z += p*o.z; acc.w += p*o.w;
      }
    }
    acc.x -= 2.0f; acc.y -= 2.0f; acc.z -= 2.0f; acc.w -= 2.0f;
    ((float4*)din)[tid] = acc;
  } else {
    const int c = tid - 128;
    ((float4*)din)[128 + c] = q4[c];
  }
  __syncthreads();

  const float4* din4 = (const float4*)din;
  for (int jj = tid; jj < DD; jj += 256) {
    const float4* wrow = (const float4*)(Wc + (long)jj * 2 * DD);
    float4 acc = {0.f, 0.f, 0.f, 0.f};
    for (int iq = 0; iq < 256; ++iq) {
      float4 w = wrow[iq]; float4 d = din4[iq];
      acc.x += w.x*d.x; acc.y += w.y*d.y; acc.z += w.z*d.z; acc.w += w.w*d.w;
    }
    dvec[jj] = bc[jj] + acc.x + acc.y + acc.z + acc.w;
  }
  __syncthreads();

  if (tid < NCLS) {
    const float4* wrow = (const float4*)(Wd + (long)tid * DD);
    const float4* dv4 = (const float4*)dvec;
    float4 acc = {0.f, 0.f, 0.f, 0.f};
    for (int iq = 0; iq < 128; ++iq) {
      float4 w = wrow[iq]; float4 d = dv4[iq];
      acc.x += w.x*d.x; acc.y += w.y*d.y; acc.z += w.z*d.z; acc.w += w.w*d.w;
    }
    out[b * NCLS + tid] = bd[tid] + acc.x + acc.y + acc.z + acc.w;
  }
}

extern "C" void kernel_launch(void* const* d_in, const int* in_sizes, int n_in,
                              void* d_out, int out_size, void* d_ws, size_t ws_size,
                              hipStream_t stream)
{
  const int*   x    = (const int*)  d_in[0];
  const int*   eos  = (const int*)  d_in[1];
  const float* emb  = (const float*)d_in[2];
  const float* W_ih = (const float*)d_in[3];
  const float* W_hh = (const float*)d_in[4];
  const float* b_ih = (const float*)d_in[5];
  const float* b_hh = (const float*)d_in[6];
  const float* Wc   = (const float*)d_in[7];
  const float* bc   = (const float*)d_in[8];
  const float* Wd   = (const float*)d_in[9];
  const float* bd   = (const float*)d_in[10];
  float* out = (float*)d_out;

  // workspace: Abuf (h2+2) | Bbuf (h1+2). Poison 0xAA = -3e-13 < 1 => "not ready".
  float* Abuf = (float*)d_ws;
  float* Bbuf = Abuf + (size_t)NB * LL * DD;

  k_scan<<<512, 256, 0, stream>>>(x, emb, W_ih, W_hh, b_ih, b_hh, Bbuf, Abuf);
  k_attn<<<NB, 256, 0, stream>>>(Abuf, eos, Wc, bc, Wd, bd, out);
}